// Round 8
// baseline (527.549 us; speedup 1.0000x reference)
//
#include <hip/hip_runtime.h>

// MoleculeGCN: 2-layer GCN, N=100000, 128->64->64, E=1600000 + self-loops.
// r8: layer pipeline = r6 known-good (fp32 float4 agg, separate gemms).
// CSR build rewritten as two-pass XCD-colored binning to kill the 102MB
// line-amplified scatter (one 64B line per 8B record, r6 counter evidence):
//   passA: edge pass -> append {src,dst} to (bucket=dst>>8, color=blockIdx&7)
//          cell; same-color blocks share an XCD -> cells fill full lines.
//          Degree count fused (absorbs the old count_deg pass).
//   passB: block per bucket; LDS fill counters; scatter confined to the
//          bucket's ~25KB CSR window -> full-line writebacks.

#define GSB 2048          // grid-stride blocks for edge-parallel work
#define SCAN_BS 256
#define COLORS 8          // one per XCD (blockIdx round-robin heuristic)
#define BUCKET_NODES 256  // nodes per bucket; window ~= 256*16*8B = 32KB
#define CELL_CAP 1024     // mean 512, sigma ~23 -> 22-sigma margin + overflow list
#define OVF_CAP 4096

// ---------- edge dtype detect (int64 vs int32), SAMPLED ----------
// int64: odd 32-bit words are high halves of node ids (< 2^17) -> all zero.
// int32: odd words are random node ids -> 16384 all-zero samples impossible.
__global__ __launch_bounds__(256) void detect_dtype_kernel(const unsigned* __restrict__ w,
                                                           int E, unsigned* __restrict__ flag) {
  __shared__ unsigned sacc;
  if (threadIdx.x == 0) sacc = 0u;
  __syncthreads();
  int ns = min(16384, E);
  unsigned acc = 0;
  for (int i = threadIdx.x; i < ns; i += 256) acc |= w[2 * i + 1];
  if (__any(acc != 0) && (threadIdx.x & 63) == 0) sacc = 1u;  // LDS, not global atomic
  __syncthreads();
  if (threadIdx.x == 0) *flag = sacc;
}

__device__ __forceinline__ int edge_src(const int* w, long e, long E, bool is64) {
  return is64 ? w[2 * e] : w[e];
}
__device__ __forceinline__ int edge_dst(const int* w, long e, long E, bool is64) {
  return is64 ? w[2 * (E + e)] : w[E + e];
}

// ---------- pass A: degree count + colored binning ----------
__global__ __launch_bounds__(256) void binpass_kernel(
    const int* __restrict__ w, int E, const unsigned* __restrict__ flag,
    int* __restrict__ cnt, int* __restrict__ cellCnt, int2* __restrict__ bins,
    int2* __restrict__ ovf, int* __restrict__ ovfCnt) {
  bool is64 = (*flag == 0u);
  int color = blockIdx.x & (COLORS - 1);
  int stride = gridDim.x * blockDim.x;
  for (int e = blockIdx.x * blockDim.x + threadIdx.x; e < E; e += stride) {
    int s = edge_src(w, e, E, is64);
    int d = edge_dst(w, e, E, is64);
    atomicAdd(&cnt[d], 1);
    int cell = (d >> 8) * COLORS + color;
    int p = atomicAdd(&cellCnt[cell], 1);
    int2 rec; rec.x = s; rec.y = d;
    if (p < CELL_CAP) bins[(size_t)cell * CELL_CAP + p] = rec;  // sequential append
    else { int q = atomicAdd(ovfCnt, 1); if (q < OVF_CAP) ovf[q] = rec; }
  }
}

// ---------- exclusive scan over cnt[N] -> offs[N+1] ----------
__global__ void scan_block_kernel(const int* __restrict__ cnt, int n, int* __restrict__ bsums) {
  __shared__ int s[SCAN_BS];
  int gid = blockIdx.x * SCAN_BS + threadIdx.x;
  s[threadIdx.x] = (gid < n) ? cnt[gid] : 0;
  __syncthreads();
  for (int st = SCAN_BS / 2; st > 0; st >>= 1) {
    if (threadIdx.x < st) s[threadIdx.x] += s[threadIdx.x + st];
    __syncthreads();
  }
  if (threadIdx.x == 0) bsums[blockIdx.x] = s[0];
}

// parallel single-block exclusive scan of bsums (chunked Hillis-Steele)
__global__ __launch_bounds__(512) void scan_bsums_kernel(int* __restrict__ bsums, int nb) {
  __shared__ int s[512];
  int carry = 0;
  for (int base = 0; base < nb; base += 512) {
    int g = base + threadIdx.x;
    int v = (g < nb) ? bsums[g] : 0;
    s[threadIdx.x] = v;
    __syncthreads();
    for (int st = 1; st < 512; st <<= 1) {
      int t = (threadIdx.x >= st) ? s[threadIdx.x - st] : 0;
      __syncthreads();
      s[threadIdx.x] += t;
      __syncthreads();
    }
    if (g < nb) bsums[g] = carry + s[threadIdx.x] - v;  // exclusive
    carry += s[511];
    __syncthreads();
  }
}

// offs (exclusive scan of cnt, + sentinel offs[n]=E) + dinv (fused)
__global__ void scan_apply_kernel(const int* __restrict__ cnt, int n,
                                  const int* __restrict__ bsums, int* __restrict__ offs,
                                  float* __restrict__ dinv, int E) {
  __shared__ int s[SCAN_BS];
  int gid = blockIdx.x * SCAN_BS + threadIdx.x;
  int v = (gid < n) ? cnt[gid] : 0;
  s[threadIdx.x] = v;
  __syncthreads();
  for (int st = 1; st < SCAN_BS; st <<= 1) {
    int t = (threadIdx.x >= st) ? s[threadIdx.x - st] : 0;
    __syncthreads();
    s[threadIdx.x] += t;
    __syncthreads();
  }
  if (gid < n) {
    offs[gid] = bsums[blockIdx.x] + s[threadIdx.x] - v;  // exclusive
    dinv[gid] = rsqrtf((float)v + 1.0f);                 // +1 = self loop
    if (gid == n - 1) offs[n] = E;                       // sentinel
  }
}

// ---------- pass B: bucket-local placement into CSR ----------
// One block per bucket. All csr writes land in the bucket's contiguous
// window [offs[node0], offs[node0+256)) -> this block's XCD L2 accumulates
// full lines. Fill counters live in LDS (global fill[] deleted).
__global__ __launch_bounds__(256) void place_kernel(
    const int2* __restrict__ bins, const int* __restrict__ cellCnt,
    const int2* __restrict__ ovf, const int* __restrict__ ovfCnt,
    const int* __restrict__ offs, const float* __restrict__ dinv,
    int2* __restrict__ csr) {
  __shared__ int lfill[BUCKET_NODES];
  int b = blockIdx.x;
  int node0 = b * BUCKET_NODES;
  for (int i = threadIdx.x; i < BUCKET_NODES; i += 256) lfill[i] = 0;
  __syncthreads();
  for (int c = 0; c < COLORS; c++) {
    int cell = b * COLORS + c;
    int m = min(cellCnt[cell], CELL_CAP);
    const int2* seg = bins + (size_t)cell * CELL_CAP;
    for (int i = threadIdx.x; i < m; i += 256) {
      int2 rec = seg[i];  // coalesced
      int d = rec.y;
      int pos = offs[d] + atomicAdd(&lfill[d - node0], 1);  // LDS atomic
      int2 out;
      out.x = rec.x;
      out.y = __float_as_int(dinv[rec.x] * dinv[d]);
      csr[pos] = out;  // confined to ~32KB window
    }
  }
  // overflow edges (astronomically rare): every block scans the tiny list
  int q = min(*ovfCnt, OVF_CAP);
  for (int i = threadIdx.x; i < q; i += 256) {
    int2 rec = ovf[i];
    int d = rec.y;
    if (d >= node0 && d < node0 + BUCKET_NODES) {
      int pos = offs[d] + atomicAdd(&lfill[d - node0], 1);
      int2 out;
      out.x = rec.x;
      out.y = __float_as_int(dinv[rec.x] * dinv[d]);
      csr[pos] = out;
    }
  }
}

// ---------- GEMM: H[n][64] = X[n][K] @ W[K][64], W staged in LDS ----------
template <int K>
__global__ __launch_bounds__(256) void gemm_kernel(const float* __restrict__ X,
                                                   const float* __restrict__ W,
                                                   float* __restrict__ H, int n) {
  __shared__ float Ws[K * 64];
  for (int i = threadIdx.x; i < K * 64; i += 256) Ws[i] = W[i];
  __syncthreads();
  int row = blockIdx.x * 256 + threadIdx.x;
  if (row >= n) return;
  const float4* xr = (const float4*)(X + (size_t)row * K);
  float acc[64];
#pragma unroll
  for (int c = 0; c < 64; c++) acc[c] = 0.f;
#pragma unroll 4
  for (int k4 = 0; k4 < K / 4; k4++) {
    float4 xv = xr[k4];
#pragma unroll
    for (int kk = 0; kk < 4; kk++) {
      float xs = (kk == 0) ? xv.x : (kk == 1) ? xv.y : (kk == 2) ? xv.z : xv.w;
      const float4* wr = (const float4*)&Ws[(k4 * 4 + kk) * 64];
#pragma unroll
      for (int c4 = 0; c4 < 16; c4++) {
        float4 wv = wr[c4];  // same address across lanes -> LDS broadcast
        acc[c4 * 4 + 0] += xs * wv.x;
        acc[c4 * 4 + 1] += xs * wv.y;
        acc[c4 * 4 + 2] += xs * wv.z;
        acc[c4 * 4 + 3] += xs * wv.w;
      }
    }
  }
  float4* ho = (float4*)(H + (size_t)row * 64);
#pragma unroll
  for (int c4 = 0; c4 < 16; c4++) {
    float4 v;
    v.x = acc[c4 * 4 + 0]; v.y = acc[c4 * 4 + 1];
    v.z = acc[c4 * 4 + 2]; v.w = acc[c4 * 4 + 3];
    ho[c4] = v;
  }
}

// ---------- aggregation (r6 known-good): 4 edge-groups x 16 lanes x float4 ----
__global__ __launch_bounds__(256) void aggregate_kernel(
    const float4* __restrict__ H4, const int* __restrict__ offs,
    const int2* __restrict__ csr,
    const float* __restrict__ dinv, const float4* __restrict__ bias4,
    float4* __restrict__ OUT4, int n, int relu) {
  int wid = (blockIdx.x * 256 + threadIdx.x) >> 6;
  int lane = threadIdx.x & 63;
  if (wid >= n) return;
  int grp = lane >> 4;
  int fl = lane & 15;
  int beg = offs[wid];
  int end = offs[wid + 1];
  float4 acc = {0.f, 0.f, 0.f, 0.f};
  for (int base = beg; base < end; base += 64) {
    int m = min(64, end - base);
    int sl = 0; float nl = 0.f;
    if (lane < m) {
      int2 rec = csr[base + lane];  // coalesced 8B
      sl = rec.x;
      nl = __int_as_float(rec.y);
    }
    int iters = ((m + 31) >> 5) << 3;  // 8 or 16; each iter covers 4 edges
    for (int j0 = 0; j0 < iters; j0 += 8) {
      int s[8]; float w[8]; float4 h[8];
#pragma unroll
      for (int t = 0; t < 8; t++) {
        int idx = (j0 + t) * 4 + grp;  // uniform within each 16-lane group
        s[t] = __shfl(sl, idx);
        w[t] = __shfl(nl, idx);
      }
#pragma unroll
      for (int t = 0; t < 8; t++) h[t] = H4[(size_t)s[t] * 16 + fl];  // 8 in flight
#pragma unroll
      for (int t = 0; t < 8; t++) {
        acc.x += h[t].x * w[t];
        acc.y += h[t].y * w[t];
        acc.z += h[t].z * w[t];
        acc.w += h[t].w * w[t];
      }
    }
  }
#pragma unroll
  for (int off2 = 32; off2 >= 16; off2 >>= 1) {
    acc.x += __shfl_xor(acc.x, off2);
    acc.y += __shfl_xor(acc.y, off2);
    acc.z += __shfl_xor(acc.z, off2);
    acc.w += __shfl_xor(acc.w, off2);
  }
  if (lane < 16) {
    float di = dinv[wid];
    float d2 = di * di;
    float4 hv = H4[(size_t)wid * 16 + fl];
    float4 bv = bias4[fl];
    acc.x += hv.x * d2 + bv.x;
    acc.y += hv.y * d2 + bv.y;
    acc.z += hv.z * d2 + bv.z;
    acc.w += hv.w * d2 + bv.w;
    if (relu) {
      acc.x = fmaxf(acc.x, 0.f);
      acc.y = fmaxf(acc.y, 0.f);
      acc.z = fmaxf(acc.z, 0.f);
      acc.w = fmaxf(acc.w, 0.f);
    }
    OUT4[(size_t)wid * 16 + fl] = acc;  // 16 lanes x 16B = coalesced 256B row
  }
}

extern "C" void kernel_launch(void* const* d_in, const int* in_sizes, int n_in,
                              void* d_out, int out_size, void* d_ws, size_t ws_size,
                              hipStream_t stream) {
  const float* x  = (const float*)d_in[0];
  const int*   ei = (const int*)d_in[1];
  const float* W1 = (const float*)d_in[2];
  const float* b1 = (const float*)d_in[3];
  const float* W2 = (const float*)d_in[4];
  const float* b2 = (const float*)d_in[5];
  float* out = (float*)d_out;

  const int N = in_sizes[0] / 128;
  const int E = in_sizes[1] / 2;
  const int nbuck = (N + BUCKET_NODES - 1) / BUCKET_NODES;
  const int ncells = nbuck * COLORS;

  // ---- workspace carve-up (256B aligned) ----
  size_t off = 0;
  char* base = (char*)d_ws;
  auto alloc = [&](size_t bytes) -> void* {
    void* p = base + off;
    off += (bytes + 255) & ~(size_t)255;
    return p;
  };
  int*      cnt     = (int*)alloc((size_t)N * 4);        // } zeroed as one region
  unsigned* flag    = (unsigned*)alloc(256);             // }
  int*      cellCnt = (int*)alloc((size_t)ncells * 4);   // }
  int*      ovfCnt  = (int*)alloc(256);                  // }
  size_t zero_bytes = off;
  int*   offs  = (int*)alloc((size_t)(N + 1) * 4);
  float* dinv  = (float*)alloc((size_t)N * 4);
  int nb = (N + SCAN_BS - 1) / SCAN_BS;
  int*   bsums = (int*)alloc((size_t)nb * 4);
  int2*  csr   = (int2*)alloc((size_t)E * 8);
  int2*  ovf   = (int2*)alloc((size_t)OVF_CAP * 8);
  // bins aliased over h1/a1: bins dead before gemm1 writes h1.
  size_t feat_bytes = (size_t)N * 64 * 4;
  size_t bins_bytes = (size_t)ncells * CELL_CAP * 8;
  size_t region = bins_bytes > 2 * feat_bytes ? bins_bytes : 2 * feat_bytes;
  char* R = (char*)alloc(region);
  int2*  bins = (int2*)R;
  float* h1   = (float*)R;
  float* a1   = (float*)(R + feat_bytes);
  float* h2   = h1;  // h1 dead after first aggregation

  hipMemsetAsync(d_ws, 0, zero_bytes, stream);

  int gemm_blocks = (N + 255) / 256;
  int agg_blocks = (N + 3) / 4;

  // ---- graph prep (shared by both layers) ----
  detect_dtype_kernel<<<1, 256, 0, stream>>>((const unsigned*)ei, E, flag);
  binpass_kernel<<<GSB, 256, 0, stream>>>(ei, E, flag, cnt, cellCnt, bins, ovf, ovfCnt);
  scan_block_kernel<<<nb, SCAN_BS, 0, stream>>>(cnt, N, bsums);
  scan_bsums_kernel<<<1, 512, 0, stream>>>(bsums, nb);
  scan_apply_kernel<<<nb, SCAN_BS, 0, stream>>>(cnt, N, bsums, offs, dinv, E);
  place_kernel<<<nbuck, 256, 0, stream>>>(bins, cellCnt, ovf, ovfCnt, offs, dinv, csr);

  // ---- layer 1 ----
  gemm_kernel<128><<<gemm_blocks, 256, 0, stream>>>(x, W1, h1, N);
  aggregate_kernel<<<agg_blocks, 256, 0, stream>>>(
      (const float4*)h1, offs, csr, dinv, (const float4*)b1, (float4*)a1, N, 1);

  // ---- layer 2 ----
  gemm_kernel<64><<<gemm_blocks, 256, 0, stream>>>(a1, W2, h2, N);
  aggregate_kernel<<<agg_blocks, 256, 0, stream>>>(
      (const float4*)h2, offs, csr, dinv, (const float4*)b2, (float4*)out, N, 0);
}